// Round 1
// baseline (657.516 us; speedup 1.0000x reference)
//
#include <hip/hip_runtime.h>
#include <hip/hip_bf16.h>

typedef __bf16 bf16_t;
typedef bf16_t bf16x8 __attribute__((ext_vector_type(8)));
typedef float  f32x4  __attribute__((ext_vector_type(4)));

constexpr int kN = 50000;   // nodes
constexpr int kE = 800000;  // edges
constexpr int kD = 128;     // D == H
constexpr int EPAD = 136;   // LDS row stride (bf16): +8 pad -> 2-way bank aliasing (free)

__device__ __forceinline__ f32x4 mfma16(bf16x8 a, bf16x8 b, f32x4 c) {
  return __builtin_amdgcn_mfma_f32_16x16x32_bf16(a, b, c, 0, 0, 0);
}
__device__ __forceinline__ float silu_f(float x) {
  return x * (1.0f / (1.0f + __expf(-x)));
}

// ---------------- prep: bf16 conversions, weight transposes, agg zero ----------------
__global__ void prep_kernel(const float* __restrict__ h,
                            const float* __restrict__ eW1, const float* __restrict__ eW2,
                            const float* __restrict__ nW1, const float* __restrict__ nW2,
                            bf16_t* __restrict__ h_bf,
                            bf16_t* __restrict__ W1T, bf16_t* __restrict__ W2T,
                            bf16_t* __restrict__ nW1T, bf16_t* __restrict__ nW2T,
                            float* __restrict__ agg) {
  const int idx = blockIdx.x * blockDim.x + threadIdx.x;
  const int stride = gridDim.x * blockDim.x;
  for (int i = idx; i < kN * kD; i += stride) {
    h_bf[i] = (bf16_t)h[i];
    agg[i] = 0.0f;
  }
  // W1T[n][k] = eW1[k][n]   (eW1 is [256][128] row-major, fan_in major)
  for (int i = idx; i < 256 * 128; i += stride) {
    const int n = i >> 8, k = i & 255;  // i = n*256 + k
    W1T[i]  = (bf16_t)eW1[k * 128 + n];
    nW1T[i] = (bf16_t)nW1[k * 128 + n];
  }
  for (int i = idx; i < 128 * 128; i += stride) {
    const int n = i >> 7, k = i & 127;  // i = n*128 + k
    W2T[i]  = (bf16_t)eW2[k * 128 + n];
    nW2T[i] = (bf16_t)nW2[k * 128 + n];
  }
}

// ---------------- fused edge kernel: gather -> MLP(2x silu) -> atomic scatter ----------------
__global__ __launch_bounds__(256, 2) void edge_kernel(
    const bf16_t* __restrict__ h_bf, const int* __restrict__ ei,
    const bf16_t* __restrict__ W1T, const bf16_t* __restrict__ W2T,
    const float* __restrict__ eb1, const float* __restrict__ eb2,
    float* __restrict__ agg) {
  __shared__ bf16_t e1[64 * EPAD];
  const int tid  = threadIdx.x;
  const int wv   = tid >> 6;
  const int lane = tid & 63;
  const int l16  = lane & 15;
  const int quad = lane >> 4;
  const int n0 = wv * 32 + l16;
  const int n1 = n0 + 16;
  const float b1v[2] = {eb1[n0], eb1[n1]};
  const float b2v[2] = {eb2[n0], eb2[n1]};

  for (int tb = blockIdx.x * 64; tb < kE; tb += gridDim.x * 64) {
    int ridx[4], cidx[4];
#pragma unroll
    for (int ms = 0; ms < 4; ++ms) {
      const int e = tb + ms * 16 + l16;
      ridx[ms] = ei[e];
      cidx[ms] = ei[kE + e];
    }

    f32x4 acc[4][2];
#pragma unroll
    for (int ms = 0; ms < 4; ++ms)
#pragma unroll
      for (int j = 0; j < 2; ++j) acc[ms][j] = (f32x4){0.f, 0.f, 0.f, 0.f};

    // GEMM1: [64,256] (gathered, concat(h[row],h[col])) @ eW1 -> acc
#pragma unroll
    for (int ks = 0; ks < 8; ++ks) {
      const bf16_t* wp = W1T + ks * 32 + quad * 8;
      const bf16x8 b0 = *(const bf16x8*)(wp + (size_t)n0 * 256);
      const bf16x8 bq = *(const bf16x8*)(wp + (size_t)n1 * 256);
#pragma unroll
      for (int ms = 0; ms < 4; ++ms) {
        const int rowi = (ks < 4) ? ridx[ms] : cidx[ms];
        const int ko = (ks & 3) * 32 + quad * 8;
        const bf16x8 a = *(const bf16x8*)(h_bf + (size_t)rowi * kD + ko);
        acc[ms][0] = mfma16(a, b0, acc[ms][0]);
        acc[ms][1] = mfma16(a, bq, acc[ms][1]);
      }
    }

    // bias + silu -> e1 tile in LDS (C-layout -> row-major bf16)
#pragma unroll
    for (int ms = 0; ms < 4; ++ms)
#pragma unroll
      for (int j = 0; j < 2; ++j) {
        const int n = wv * 32 + j * 16 + l16;
#pragma unroll
        for (int r = 0; r < 4; ++r) {
          const int m = ms * 16 + quad * 4 + r;
          e1[m * EPAD + n] = (bf16_t)silu_f(acc[ms][j][r] + b1v[j]);
        }
      }
    __syncthreads();

    // GEMM2: e1 [64,128] @ eW2 -> acc2
    f32x4 acc2[4][2];
#pragma unroll
    for (int ms = 0; ms < 4; ++ms)
#pragma unroll
      for (int j = 0; j < 2; ++j) acc2[ms][j] = (f32x4){0.f, 0.f, 0.f, 0.f};
#pragma unroll
    for (int ks = 0; ks < 4; ++ks) {
      const bf16_t* wp = W2T + ks * 32 + quad * 8;
      const bf16x8 b0 = *(const bf16x8*)(wp + (size_t)n0 * 128);
      const bf16x8 bq = *(const bf16x8*)(wp + (size_t)n1 * 128);
#pragma unroll
      for (int ms = 0; ms < 4; ++ms) {
        const bf16x8 a = *(const bf16x8*)&e1[(ms * 16 + l16) * EPAD + ks * 32 + quad * 8];
        acc2[ms][0] = mfma16(a, b0, acc2[ms][0]);
        acc2[ms][1] = mfma16(a, bq, acc2[ms][1]);
      }
    }
    __syncthreads();  // all waves done reading e1 before next iteration overwrites it

    // bias + silu + atomic scatter-add into agg[row]
#pragma unroll
    for (int ms = 0; ms < 4; ++ms) {
      const int4 rr = *(const int4*)(ei + tb + ms * 16 + quad * 4);
      const int rows[4] = {rr.x, rr.y, rr.z, rr.w};
#pragma unroll
      for (int j = 0; j < 2; ++j) {
        const int n = wv * 32 + j * 16 + l16;
#pragma unroll
        for (int r = 0; r < 4; ++r) {
          const float v = silu_f(acc2[ms][j][r] + b2v[j]);
          atomicAdd(agg + (size_t)rows[r] * kD + n, v);
        }
      }
    }
  }
}

// ---------------- node kernel: [h | agg] MLP + residual ----------------
__global__ __launch_bounds__(256, 2) void node_kernel(
    const bf16_t* __restrict__ h_bf, const float* __restrict__ h,
    const float* __restrict__ agg,
    const bf16_t* __restrict__ nW1T, const bf16_t* __restrict__ nW2T,
    const float* __restrict__ nb1, const float* __restrict__ nb2,
    float* __restrict__ out) {
  __shared__ bf16_t t1[64 * EPAD];
  const int tid  = threadIdx.x;
  const int wv   = tid >> 6;
  const int lane = tid & 63;
  const int l16  = lane & 15;
  const int quad = lane >> 4;
  const int n0 = wv * 32 + l16;
  const int n1 = n0 + 16;
  const float b1v[2] = {nb1[n0], nb1[n1]};
  const float b2v[2] = {nb2[n0], nb2[n1]};

  for (int tb = blockIdx.x * 64; tb < kN; tb += gridDim.x * 64) {
    f32x4 acc[4][2];
#pragma unroll
    for (int ms = 0; ms < 4; ++ms)
#pragma unroll
      for (int j = 0; j < 2; ++j) acc[ms][j] = (f32x4){0.f, 0.f, 0.f, 0.f};

    // GEMM1: [64,256] ([h | agg]) @ nW1
#pragma unroll
    for (int ks = 0; ks < 8; ++ks) {
      const bf16_t* wp = nW1T + ks * 32 + quad * 8;
      const bf16x8 b0 = *(const bf16x8*)(wp + (size_t)n0 * 256);
      const bf16x8 bq = *(const bf16x8*)(wp + (size_t)n1 * 256);
#pragma unroll
      for (int ms = 0; ms < 4; ++ms) {
        int node = tb + ms * 16 + l16;
        node = node < kN ? node : kN - 1;  // clamp for partial last tile
        bf16x8 a;
        if (ks < 4) {
          a = *(const bf16x8*)(h_bf + (size_t)node * kD + ks * 32 + quad * 8);
        } else {
          const float4* p = (const float4*)(agg + (size_t)node * kD + (ks - 4) * 32 + quad * 8);
          const float4 f0 = p[0], f1 = p[1];
          a = (bf16x8){(bf16_t)f0.x, (bf16_t)f0.y, (bf16_t)f0.z, (bf16_t)f0.w,
                       (bf16_t)f1.x, (bf16_t)f1.y, (bf16_t)f1.z, (bf16_t)f1.w};
        }
        acc[ms][0] = mfma16(a, b0, acc[ms][0]);
        acc[ms][1] = mfma16(a, bq, acc[ms][1]);
      }
    }

    // bias + silu -> t1
#pragma unroll
    for (int ms = 0; ms < 4; ++ms)
#pragma unroll
      for (int j = 0; j < 2; ++j) {
        const int n = wv * 32 + j * 16 + l16;
#pragma unroll
        for (int r = 0; r < 4; ++r) {
          const int m = ms * 16 + quad * 4 + r;
          t1[m * EPAD + n] = (bf16_t)silu_f(acc[ms][j][r] + b1v[j]);
        }
      }
    __syncthreads();

    // GEMM2: t1 @ nW2 (no silu)
    f32x4 acc2[4][2];
#pragma unroll
    for (int ms = 0; ms < 4; ++ms)
#pragma unroll
      for (int j = 0; j < 2; ++j) acc2[ms][j] = (f32x4){0.f, 0.f, 0.f, 0.f};
#pragma unroll
    for (int ks = 0; ks < 4; ++ks) {
      const bf16_t* wp = nW2T + ks * 32 + quad * 8;
      const bf16x8 b0 = *(const bf16x8*)(wp + (size_t)n0 * 128);
      const bf16x8 bq = *(const bf16x8*)(wp + (size_t)n1 * 128);
#pragma unroll
      for (int ms = 0; ms < 4; ++ms) {
        const bf16x8 a = *(const bf16x8*)&t1[(ms * 16 + l16) * EPAD + ks * 32 + quad * 8];
        acc2[ms][0] = mfma16(a, b0, acc2[ms][0]);
        acc2[ms][1] = mfma16(a, bq, acc2[ms][1]);
      }
    }
    __syncthreads();

    // epilogue: out = h + (acc2 + nb2)
#pragma unroll
    for (int ms = 0; ms < 4; ++ms)
#pragma unroll
      for (int j = 0; j < 2; ++j) {
        const int n = wv * 32 + j * 16 + l16;
#pragma unroll
        for (int r = 0; r < 4; ++r) {
          const int node = tb + ms * 16 + quad * 4 + r;
          if (node < kN) {
            const size_t o = (size_t)node * kD + n;
            out[o] = h[o] + acc2[ms][j][r] + b2v[j];
          }
        }
      }
  }
}

// ---------------- launch ----------------
extern "C" void kernel_launch(void* const* d_in, const int* in_sizes, int n_in,
                              void* d_out, int out_size, void* d_ws, size_t ws_size,
                              hipStream_t stream) {
  const float* h   = (const float*)d_in[0];
  const int*   ei  = (const int*)d_in[1];
  const float* eW1 = (const float*)d_in[2];
  const float* eb1 = (const float*)d_in[3];
  const float* eW2 = (const float*)d_in[4];
  const float* eb2 = (const float*)d_in[5];
  const float* nW1 = (const float*)d_in[6];
  const float* nb1 = (const float*)d_in[7];
  const float* nW2 = (const float*)d_in[8];
  const float* nb2 = (const float*)d_in[9];
  float* out = (float*)d_out;

  char* ws = (char*)d_ws;
  bf16_t* h_bf = (bf16_t*)(ws + 0);         // 12,800,000 B
  bf16_t* W1T  = (bf16_t*)(ws + 12800000);  // 65,536 B
  bf16_t* W2T  = (bf16_t*)(ws + 12865536);  // 32,768 B
  bf16_t* nW1T = (bf16_t*)(ws + 12898304);  // 65,536 B
  bf16_t* nW2T = (bf16_t*)(ws + 12963840);  // 32,768 B
  float*  agg  = (float*)(ws + 12996608);   // 25,600,000 B  (total ~38.6 MB)

  prep_kernel<<<4096, 256, 0, stream>>>(h, eW1, eW2, nW1, nW2,
                                        h_bf, W1T, W2T, nW1T, nW2T, agg);
  edge_kernel<<<kE / 64, 256, 0, stream>>>(h_bf, ei, W1T, W2T, eb1, eb2, agg);
  node_kernel<<<(kN + 63) / 64, 256, 0, stream>>>(h_bf, h, agg, nW1T, nW2T, nb1, nb2, out);
}

// Round 2
// 586.683 us; speedup vs baseline: 1.1207x; 1.1207x over previous
//
#include <hip/hip_runtime.h>
#include <hip/hip_bf16.h>

typedef __bf16 bf16_t;
typedef bf16_t bf16x8 __attribute__((ext_vector_type(8)));
typedef float  f32x4  __attribute__((ext_vector_type(4)));

constexpr int kN = 50000;   // nodes
constexpr int kE = 800000;  // edges
constexpr int kD = 128;     // D == H
constexpr int EPAD = 136;   // e1 LDS row stride (bf16): +8 pad -> 2-way aliasing (free)

__device__ __forceinline__ f32x4 mfma16(bf16x8 a, bf16x8 b, f32x4 c) {
  return __builtin_amdgcn_mfma_f32_16x16x32_bf16(a, b, c, 0, 0, 0);
}
__device__ __forceinline__ float silu_f(float x) {
  return x * (1.0f / (1.0f + __expf(-x)));
}

// ---------------- prep: bf16 conversions, weight transposes, zero agg+hist ----------------
__global__ void prep_kernel(const float* __restrict__ h,
                            const float* __restrict__ eW1, const float* __restrict__ eW2,
                            const float* __restrict__ nW1, const float* __restrict__ nW2,
                            bf16_t* __restrict__ h_bf,
                            bf16_t* __restrict__ W1T, bf16_t* __restrict__ W2T,
                            bf16_t* __restrict__ nW1T, bf16_t* __restrict__ nW2T,
                            float* __restrict__ agg, int* __restrict__ hist) {
  const int idx = blockIdx.x * blockDim.x + threadIdx.x;
  const int stride = gridDim.x * blockDim.x;
  for (int i = idx; i < kN * kD; i += stride) {
    h_bf[i] = (bf16_t)h[i];
    agg[i] = 0.0f;
  }
  for (int i = idx; i < kN; i += stride) hist[i] = 0;
  // W1T[n][k] = eW1[k][n]   (eW1 is [256][128] row-major, fan_in major)
  for (int i = idx; i < 256 * 128; i += stride) {
    const int n = i >> 8, k = i & 255;
    W1T[i]  = (bf16_t)eW1[k * 128 + n];
    nW1T[i] = (bf16_t)nW1[k * 128 + n];
  }
  for (int i = idx; i < 128 * 128; i += stride) {
    const int n = i >> 7, k = i & 127;
    W2T[i]  = (bf16_t)eW2[k * 128 + n];
    nW2T[i] = (bf16_t)nW2[k * 128 + n];
  }
}

// ---------------- CSR build: histogram -> scan -> bucket ----------------
__global__ void hist_kernel(const int* __restrict__ ei, int* __restrict__ hist) {
  const int idx = blockIdx.x * blockDim.x + threadIdx.x;
  const int stride = gridDim.x * blockDim.x;
  for (int e = idx; e < kE; e += stride) atomicAdd(&hist[ei[e]], 1);
}

// single-block exclusive scan: cursor[i] = sum(hist[0..i))
__global__ void scan_kernel(const int* __restrict__ hist, int* __restrict__ cursor) {
  __shared__ int partial[1024];
  const int tid = threadIdx.x;
  constexpr int CH = (kN + 1023) / 1024;  // 49
  const int base = tid * CH;
  int s = 0;
#pragma unroll
  for (int i = 0; i < CH; ++i) {
    const int j = base + i;
    if (j < kN) s += hist[j];
  }
  partial[tid] = s;
  __syncthreads();
  for (int off = 1; off < 1024; off <<= 1) {
    int v = 0;
    if (tid >= off) v = partial[tid - off];
    __syncthreads();
    if (tid >= off) partial[tid] += v;
    __syncthreads();
  }
  int run = (tid == 0) ? 0 : partial[tid - 1];
#pragma unroll
  for (int i = 0; i < CH; ++i) {
    const int j = base + i;
    if (j < kN) {
      cursor[j] = run;
      run += hist[j];
    }
  }
}

__global__ void bucket_kernel(const int* __restrict__ ei, int* __restrict__ cursor,
                              int* __restrict__ slot_row, int* __restrict__ slot_col) {
  const int idx = blockIdx.x * blockDim.x + threadIdx.x;
  const int stride = gridDim.x * blockDim.x;
  for (int e = idx; e < kE; e += stride) {
    const int r = ei[e];
    const int c = ei[kE + e];
    const int pos = atomicAdd(&cursor[r], 1);
    slot_row[pos] = r;
    slot_col[pos] = c;
  }
}

// ---------------- fused edge kernel (CSR order): gather -> MLP -> segmented reduce -> few atomics ----------------
__global__ __launch_bounds__(256, 4) void edge_kernel(
    const bf16_t* __restrict__ h_bf,
    const int* __restrict__ slot_row, const int* __restrict__ slot_col,
    const bf16_t* __restrict__ W1T, const bf16_t* __restrict__ W2T,
    const float* __restrict__ eb1, const float* __restrict__ eb2,
    float* __restrict__ agg) {
  __shared__ __align__(16) char smem[64 * 128 * 4 + 256];
  bf16_t* e1 = (bf16_t*)smem;               // [64][EPAD] bf16, 17408 B (phase 1)
  float* sval = (float*)smem;               // [64][128] fp32, 32768 B (phase 2, reuses)
  int* rows_lds = (int*)(smem + 64 * 128 * 4);  // [64]

  const int tid  = threadIdx.x;
  const int wv   = tid >> 6;
  const int lane = tid & 63;
  const int l16  = lane & 15;
  const int quad = lane >> 4;
  const int n0 = wv * 32 + l16;
  const int n1 = n0 + 16;
  const float b1v[2] = {eb1[n0], eb1[n1]};
  const float b2v[2] = {eb2[n0], eb2[n1]};

  const int tb = blockIdx.x * 64;  // grid sized exactly kE/64

  if (tid < 64) rows_lds[tid] = slot_row[tb + tid];

  int ridx[4], cidx[4];
#pragma unroll
  for (int ms = 0; ms < 4; ++ms) {
    const int s = tb + ms * 16 + l16;
    ridx[ms] = slot_row[s];
    cidx[ms] = slot_col[s];
  }

  f32x4 acc[4][2];
#pragma unroll
  for (int ms = 0; ms < 4; ++ms)
#pragma unroll
    for (int j = 0; j < 2; ++j) acc[ms][j] = (f32x4){0.f, 0.f, 0.f, 0.f};

  // GEMM1: [64,256] (concat(h[row],h[col]), rows nearly-sorted) @ eW1
#pragma unroll
  for (int ks = 0; ks < 8; ++ks) {
    const bf16_t* wp = W1T + ks * 32 + quad * 8;
    const bf16x8 b0 = *(const bf16x8*)(wp + (size_t)n0 * 256);
    const bf16x8 bq = *(const bf16x8*)(wp + (size_t)n1 * 256);
#pragma unroll
    for (int ms = 0; ms < 4; ++ms) {
      const int rowi = (ks < 4) ? ridx[ms] : cidx[ms];
      const int ko = (ks & 3) * 32 + quad * 8;
      const bf16x8 a = *(const bf16x8*)(h_bf + (size_t)rowi * kD + ko);
      acc[ms][0] = mfma16(a, b0, acc[ms][0]);
      acc[ms][1] = mfma16(a, bq, acc[ms][1]);
    }
  }

  // bias + silu -> e1 (C-layout -> row-major bf16)
#pragma unroll
  for (int ms = 0; ms < 4; ++ms)
#pragma unroll
    for (int j = 0; j < 2; ++j) {
      const int n = wv * 32 + j * 16 + l16;
#pragma unroll
      for (int r = 0; r < 4; ++r) {
        const int m = ms * 16 + quad * 4 + r;
        e1[m * EPAD + n] = (bf16_t)silu_f(acc[ms][j][r] + b1v[j]);
      }
    }
  __syncthreads();

  // GEMM2: e1 [64,128] @ eW2
  f32x4 acc2[4][2];
#pragma unroll
  for (int ms = 0; ms < 4; ++ms)
#pragma unroll
    for (int j = 0; j < 2; ++j) acc2[ms][j] = (f32x4){0.f, 0.f, 0.f, 0.f};
#pragma unroll
  for (int ks = 0; ks < 4; ++ks) {
    const bf16_t* wp = W2T + ks * 32 + quad * 8;
    const bf16x8 b0 = *(const bf16x8*)(wp + (size_t)n0 * 128);
    const bf16x8 bq = *(const bf16x8*)(wp + (size_t)n1 * 128);
#pragma unroll
    for (int ms = 0; ms < 4; ++ms) {
      const bf16x8 a = *(const bf16x8*)&e1[(ms * 16 + l16) * EPAD + ks * 32 + quad * 8];
      acc2[ms][0] = mfma16(a, b0, acc2[ms][0]);
      acc2[ms][1] = mfma16(a, bq, acc2[ms][1]);
    }
  }
  __syncthreads();  // e1 reads done; smem becomes sval

  // bias + silu -> sval fp32 tile [m][n]
#pragma unroll
  for (int ms = 0; ms < 4; ++ms)
#pragma unroll
    for (int j = 0; j < 2; ++j) {
      const int n = wv * 32 + j * 16 + l16;
#pragma unroll
      for (int r = 0; r < 4; ++r) {
        const int m = ms * 16 + quad * 4 + r;
        sval[m * 128 + n] = silu_f(acc2[ms][j][r] + b2v[j]);
      }
    }
  __syncthreads();

  // segmented reduction over m (rows nondecreasing), one atomic per (node,col) segment
  {
    const int col = tid & 127;
    const int m0 = (tid >> 7) * 32;
    float a = 0.0f;
    int cur = rows_lds[m0];
#pragma unroll 8
    for (int m = m0; m < m0 + 32; ++m) {
      const int row = rows_lds[m];
      if (row != cur) {
        atomicAdd(agg + (size_t)cur * kD + col, a);
        a = 0.0f;
        cur = row;
      }
      a += sval[m * 128 + col];
    }
    atomicAdd(agg + (size_t)cur * kD + col, a);
  }
}

// ---------------- node kernel: [h | agg] MLP + residual ----------------
__global__ __launch_bounds__(256, 2) void node_kernel(
    const bf16_t* __restrict__ h_bf, const float* __restrict__ h,
    const float* __restrict__ agg,
    const bf16_t* __restrict__ nW1T, const bf16_t* __restrict__ nW2T,
    const float* __restrict__ nb1, const float* __restrict__ nb2,
    float* __restrict__ out) {
  __shared__ bf16_t t1[64 * EPAD];
  const int tid  = threadIdx.x;
  const int wv   = tid >> 6;
  const int lane = tid & 63;
  const int l16  = lane & 15;
  const int quad = lane >> 4;
  const int n0 = wv * 32 + l16;
  const int n1 = n0 + 16;
  const float b1v[2] = {nb1[n0], nb1[n1]};
  const float b2v[2] = {nb2[n0], nb2[n1]};

  for (int tb = blockIdx.x * 64; tb < kN; tb += gridDim.x * 64) {
    f32x4 acc[4][2];
#pragma unroll
    for (int ms = 0; ms < 4; ++ms)
#pragma unroll
      for (int j = 0; j < 2; ++j) acc[ms][j] = (f32x4){0.f, 0.f, 0.f, 0.f};

#pragma unroll
    for (int ks = 0; ks < 8; ++ks) {
      const bf16_t* wp = nW1T + ks * 32 + quad * 8;
      const bf16x8 b0 = *(const bf16x8*)(wp + (size_t)n0 * 256);
      const bf16x8 bq = *(const bf16x8*)(wp + (size_t)n1 * 256);
#pragma unroll
      for (int ms = 0; ms < 4; ++ms) {
        int node = tb + ms * 16 + l16;
        node = node < kN ? node : kN - 1;
        bf16x8 a;
        if (ks < 4) {
          a = *(const bf16x8*)(h_bf + (size_t)node * kD + ks * 32 + quad * 8);
        } else {
          const float4* p = (const float4*)(agg + (size_t)node * kD + (ks - 4) * 32 + quad * 8);
          const float4 f0 = p[0], f1 = p[1];
          a = (bf16x8){(bf16_t)f0.x, (bf16_t)f0.y, (bf16_t)f0.z, (bf16_t)f0.w,
                       (bf16_t)f1.x, (bf16_t)f1.y, (bf16_t)f1.z, (bf16_t)f1.w};
        }
        acc[ms][0] = mfma16(a, b0, acc[ms][0]);
        acc[ms][1] = mfma16(a, bq, acc[ms][1]);
      }
    }

#pragma unroll
    for (int ms = 0; ms < 4; ++ms)
#pragma unroll
      for (int j = 0; j < 2; ++j) {
        const int n = wv * 32 + j * 16 + l16;
#pragma unroll
        for (int r = 0; r < 4; ++r) {
          const int m = ms * 16 + quad * 4 + r;
          t1[m * EPAD + n] = (bf16_t)silu_f(acc[ms][j][r] + b1v[j]);
        }
      }
    __syncthreads();

    f32x4 acc2[4][2];
#pragma unroll
    for (int ms = 0; ms < 4; ++ms)
#pragma unroll
      for (int j = 0; j < 2; ++j) acc2[ms][j] = (f32x4){0.f, 0.f, 0.f, 0.f};
#pragma unroll
    for (int ks = 0; ks < 4; ++ks) {
      const bf16_t* wp = nW2T + ks * 32 + quad * 8;
      const bf16x8 b0 = *(const bf16x8*)(wp + (size_t)n0 * 128);
      const bf16x8 bq = *(const bf16x8*)(wp + (size_t)n1 * 128);
#pragma unroll
      for (int ms = 0; ms < 4; ++ms) {
        const bf16x8 a = *(const bf16x8*)&t1[(ms * 16 + l16) * EPAD + ks * 32 + quad * 8];
        acc2[ms][0] = mfma16(a, b0, acc2[ms][0]);
        acc2[ms][1] = mfma16(a, bq, acc2[ms][1]);
      }
    }
    __syncthreads();

#pragma unroll
    for (int ms = 0; ms < 4; ++ms)
#pragma unroll
      for (int j = 0; j < 2; ++j) {
        const int n = wv * 32 + j * 16 + l16;
#pragma unroll
        for (int r = 0; r < 4; ++r) {
          const int node = tb + ms * 16 + quad * 4 + r;
          if (node < kN) {
            const size_t o = (size_t)node * kD + n;
            out[o] = h[o] + acc2[ms][j][r] + b2v[j];
          }
        }
      }
  }
}

// ---------------- launch ----------------
extern "C" void kernel_launch(void* const* d_in, const int* in_sizes, int n_in,
                              void* d_out, int out_size, void* d_ws, size_t ws_size,
                              hipStream_t stream) {
  const float* h   = (const float*)d_in[0];
  const int*   ei  = (const int*)d_in[1];
  const float* eW1 = (const float*)d_in[2];
  const float* eb1 = (const float*)d_in[3];
  const float* eW2 = (const float*)d_in[4];
  const float* eb2 = (const float*)d_in[5];
  const float* nW1 = (const float*)d_in[6];
  const float* nb1 = (const float*)d_in[7];
  const float* nW2 = (const float*)d_in[8];
  const float* nb2 = (const float*)d_in[9];
  float* out = (float*)d_out;

  char* ws = (char*)d_ws;
  size_t off = 0;
  auto alloc = [&](size_t bytes) {
    void* p = ws + off;
    off += (bytes + 255) & ~(size_t)255;
    return p;
  };
  bf16_t* h_bf = (bf16_t*)alloc((size_t)kN * kD * 2);   // 12.8 MB
  bf16_t* W1T  = (bf16_t*)alloc(256 * 128 * 2);
  bf16_t* W2T  = (bf16_t*)alloc(128 * 128 * 2);
  bf16_t* nW1T = (bf16_t*)alloc(256 * 128 * 2);
  bf16_t* nW2T = (bf16_t*)alloc(128 * 128 * 2);
  float*  agg  = (float*)alloc((size_t)kN * kD * 4);    // 25.6 MB
  int* hist     = (int*)alloc((size_t)kN * 4);
  int* cursor   = (int*)alloc((size_t)kN * 4);
  int* slot_row = (int*)alloc((size_t)kE * 4);          // 3.2 MB
  int* slot_col = (int*)alloc((size_t)kE * 4);          // 3.2 MB

  prep_kernel<<<2048, 256, 0, stream>>>(h, eW1, eW2, nW1, nW2,
                                        h_bf, W1T, W2T, nW1T, nW2T, agg, hist);
  hist_kernel<<<1024, 256, 0, stream>>>(ei, hist);
  scan_kernel<<<1, 1024, 0, stream>>>(hist, cursor);
  bucket_kernel<<<1024, 256, 0, stream>>>(ei, cursor, slot_row, slot_col);
  edge_kernel<<<kE / 64, 256, 0, stream>>>(h_bf, slot_row, slot_col, W1T, W2T, eb1, eb2, agg);
  node_kernel<<<(kN + 63) / 64, 256, 0, stream>>>(h_bf, h, agg, nW1T, nW2T, nb1, nb2, out);
}